// Round 18
// baseline (263.852 us; speedup 1.0000x reference)
//
#include <hip/hip_runtime.h>
#include <hip/hip_bf16.h>
#include <math.h>

typedef __bf16 bf16x8 __attribute__((ext_vector_type(8)));
typedef float f32x4 __attribute__((ext_vector_type(4)));

#define DD 768
#define HH 12
#define MLPD 3072
#define QSCALE 0.036084391824351615f  // 1/sqrt(768)

// sigmoid-form tanh-approx gelu: max abs err ~3e-4, ~8 VALU ops (1 hw exp)
__device__ __forceinline__ float gelu_fast(float x) {
    float y = 1.5957691216057308f * x + 0.07135481283154893f * x * x * x;
    return x * __builtin_amdgcn_rcpf(1.0f + __expf(-y));
}

__device__ __forceinline__ void gload16(const void* g, void* l) {
    __builtin_amdgcn_global_load_lds(
        (const __attribute__((address_space(1))) unsigned int*)g,
        (__attribute__((address_space(3))) unsigned int*)l, 16, 0, 0);
}

// barrier the compiler cannot reorder memory ops across (rule #18)
__device__ __forceinline__ void hard_barrier() {
    __builtin_amdgcn_sched_barrier(0);
    __builtin_amdgcn_s_barrier();
    __builtin_amdgcn_sched_barrier(0);
}

// ---------- LayerNorm row body: one wave handles one row of 768 ----------
__device__ __forceinline__ void ln_row(const float* __restrict__ xr,
                                       const float* __restrict__ g,
                                       const float* __restrict__ b,
                                       __bf16* __restrict__ orow, int lane) {
    float4 v[3];
    float s = 0.f, ss = 0.f;
#pragma unroll
    for (int i = 0; i < 3; ++i) {
        v[i] = *reinterpret_cast<const float4*>(&xr[(i * 64 + lane) * 4]);
        s += v[i].x + v[i].y + v[i].z + v[i].w;
        ss += v[i].x * v[i].x + v[i].y * v[i].y + v[i].z * v[i].z + v[i].w * v[i].w;
    }
#pragma unroll
    for (int m = 1; m < 64; m <<= 1) {
        s += __shfl_xor(s, m);
        ss += __shfl_xor(ss, m);
    }
    float mu = s * (1.0f / DD);
    float rstd = rsqrtf(ss * (1.0f / DD) - mu * mu + 1e-5f);
#pragma unroll
    for (int i = 0; i < 3; ++i) {
        int c = (i * 64 + lane) * 4;
        float4 gv = *reinterpret_cast<const float4*>(&g[c]);
        float4 bv = *reinterpret_cast<const float4*>(&b[c]);
        union { __bf16 h[4]; uint2 u; } o;
        o.h[0] = (__bf16)((v[i].x - mu) * rstd * gv.x + bv.x);
        o.h[1] = (__bf16)((v[i].y - mu) * rstd * gv.y + bv.y);
        o.h[2] = (__bf16)((v[i].z - mu) * rstd * gv.z + bv.z);
        o.h[3] = (__bf16)((v[i].w - mu) * rstd * gv.w + bv.w);
        *reinterpret_cast<uint2*>(&orow[c]) = o.u;
    }
}

// ---------- standalone LN (4 rows per 256-thr block) for LN2 ----------
__global__ __launch_bounds__(256) void ln_kernel(const float* __restrict__ X,
                                                 const float* __restrict__ g,
                                                 const float* __restrict__ b,
                                                 __bf16* __restrict__ O) {
    int row = blockIdx.x * 4 + (threadIdx.x >> 6);
    ln_row(X + (size_t)row * DD, g, b, O + (size_t)row * DD, threadIdx.x & 63);
}

// ---------- fused prep: blocks [0,1728) weight transposes, [1728,3776) LN1 ----------
__global__ __launch_bounds__(256) void prep_kernel(
    const float* __restrict__ Wq, const float* __restrict__ Wk,
    const float* __restrict__ Wv, const float* __restrict__ Wo,
    const float* __restrict__ W1, const float* __restrict__ W2,
    __bf16* __restrict__ wqkv, __bf16* __restrict__ wo,
    __bf16* __restrict__ w1, __bf16* __restrict__ w2,
    const float* __restrict__ x, const float* __restrict__ ln1_g,
    const float* __restrict__ ln1_b, __bf16* __restrict__ h) {
    __shared__ float tile[64][65];
    int blk = blockIdx.x;
    if (blk >= 1728) {  // LN1: 4 rows per block
        int row = (blk - 1728) * 4 + (threadIdx.x >> 6);
        ln_row(x + (size_t)row * DD, ln1_g, ln1_b, h + (size_t)row * DD, threadIdx.x & 63);
        return;
    }
    const float* W; __bf16* Wt; int K, N, tk, tn;
    if (blk < 432) {
        int wsel = blk / 144, r = blk - wsel * 144;
        W = wsel == 0 ? Wq : (wsel == 1 ? Wk : Wv);
        Wt = wqkv + (size_t)wsel * 768 * 768;
        K = 768; N = 768; tk = r % 12; tn = r / 12;
    } else if (blk < 576) {
        int r = blk - 432; W = Wo; Wt = wo; K = 768; N = 768; tk = r % 12; tn = r / 12;
    } else if (blk < 1152) {
        int r = blk - 576; W = W1; Wt = w1; K = 768; N = 3072; tk = r % 12; tn = r / 12;
    } else {
        int r = blk - 1152; W = W2; Wt = w2; K = 3072; N = 768; tk = r % 48; tn = r / 48;
    }
    int k0 = tk * 64, n0 = tn * 64;
    int t = threadIdx.x;
    int tr = t >> 6, tc = t & 63;
#pragma unroll
    for (int i = 0; i < 16; ++i) {
        int row = i * 4 + tr;
        tile[row][tc] = W[(size_t)(k0 + row) * N + n0 + tc];
    }
    __syncthreads();
#pragma unroll
    for (int i = 0; i < 16; ++i) {
        int row = i * 4 + tr;
        Wt[(size_t)(n0 + row) * K + k0 + tc] = (__bf16)tile[tc][row];
    }
}

// ---------- pipelined GEMM (round-16 engine + XCD swizzle): 128x128, BK=64 ----------
// 512 threads = 8 waves (2M x 4N), 64x32 out/wave; 2 LDS bufs (64 KB) -> 2 blocks/CU,
// 4 waves/SIMD. Depth-1 counted vmcnt(4); hard barriers (rule 18); source-chunk
// swizzle + XOR'd reads (rule 21, 0 conflicts). Launched on a 1-D grid with
// T1 XCD-chunked bijective swizzle (all grids % 8 == 0): consecutive ids within an
// XCD chunk share B-panels -> per-XCD L2 locality.
// EPI 0: fused QKV.  EPI 2: +resid fp32.  EPI 3: gelu bf16.  EPI 4: gelu+resid fp32.
template <int EPI>
__global__ __launch_bounds__(512, 4) void gemm_pl(
    const __bf16* __restrict__ A, const __bf16* __restrict__ Bt,
    const float* __restrict__ b0, const float* __restrict__ b1, const float* __restrict__ b2,
    void* __restrict__ o0, void* __restrict__ o1, void* __restrict__ o2,
    const float* __restrict__ resid, int gx, int M, int N, int K) {
    extern __shared__ __bf16 lds[];
    __bf16* As = lds;            // 2 x 128x64
    __bf16* Bs = lds + 16384;    // 2 x 128x64
    const int nblk = gx * (N >> 7);
    const int cpx = nblk >> 3;                       // chunk size per XCD (nblk%8==0)
    const int swzid = (blockIdx.x & 7) * cpx + (blockIdx.x >> 3);
    const int bx = swzid % gx, by = swzid / gx;      // bx fastest: same-by share B-panel
    const int t = threadIdx.x;
    const int w = t >> 6, lane = t & 63;
    const int wm = w >> 2, wn = w & 3;   // 2M x 4N
    const int lr = lane & 15, lg = lane >> 4;
    const int m0 = bx * 128, n0 = by * 128;
    const int lrow8 = lane >> 3;
    const int cSwz = ((lane & 7) ^ lrow8) * 8;

    const __bf16* aSrc = A + (size_t)(m0 + w * 16 + lrow8) * K + cSwz;
    const __bf16* bSrc = Bt + (size_t)(n0 + w * 16 + lrow8) * K + cSwz;
    const int ldsW = w * 16 * 64;

    const int nt = K >> 6;
    f32x4 acc[4][2] = {};

    auto stage = [&](int T) {  // 4 loads/thread
        const int buf = (T & 1) * 8192;
#pragma unroll
        for (int c = 0; c < 2; ++c)
            gload16(aSrc + (size_t)(c * 8) * K + T * 64, &As[buf + ldsW + c * 8 * 64]);
#pragma unroll
        for (int c = 0; c < 2; ++c)
            gload16(bSrc + (size_t)(c * 8) * K + T * 64, &Bs[buf + ldsW + c * 8 * 64]);
    };

    stage(0);
    for (int T = 0; T < nt; ++T) {
        if (T + 1 < nt) {
            stage(T + 1);
            asm volatile("s_waitcnt vmcnt(4)" ::: "memory");  // tile T's 4 landed
        } else {
            asm volatile("s_waitcnt vmcnt(0)" ::: "memory");
        }
        hard_barrier();  // all waves' tile-T loads landed; reads pinned below
        const int buf = (T & 1) * 8192;
#pragma unroll
        for (int kg = 0; kg < 2; ++kg) {
            bf16x8 af[4], bfr[2];
#pragma unroll
            for (int i = 0; i < 4; ++i)
                af[i] = *reinterpret_cast<const bf16x8*>(
                    &As[buf + (wm * 64 + i * 16 + lr) * 64 + (((kg << 2) | lg) ^ (lr & 7)) * 8]);
#pragma unroll
            for (int j = 0; j < 2; ++j)
                bfr[j] = *reinterpret_cast<const bf16x8*>(
                    &Bs[buf + (wn * 32 + j * 16 + lr) * 64 + (((kg << 2) | lg) ^ (lr & 7)) * 8]);
#pragma unroll
            for (int i = 0; i < 4; ++i)
#pragma unroll
                for (int j = 0; j < 2; ++j)
                    acc[i][j] = __builtin_amdgcn_mfma_f32_16x16x32_bf16(bfr[j], af[i], acc[i][j], 0, 0, 0);
        }
        hard_barrier();  // reads of buf done before next stage overwrites it
    }

#pragma unroll
    for (int i = 0; i < 4; ++i) {
        const int m = m0 + wm * 64 + i * 16 + lr;
        const int bI = m >> 10, ntok = m & 1023;
#pragma unroll
        for (int j = 0; j < 2; ++j) {
            const int n = n0 + wn * 32 + j * 16 + lg * 4;
            if (EPI == 0) {
                const int wid = n / 768;
                const int cc0 = n - wid * 768;
                const int hh = cc0 >> 6, f0 = cc0 & 63;
                const float* bsel = (wid == 0 ? b0 : (wid == 1 ? b1 : b2));
                const float4 bv = *reinterpret_cast<const float4*>(&bsel[cc0]);
                const float v0 = acc[i][j][0] + bv.x, v1 = acc[i][j][1] + bv.y;
                const float v2 = acc[i][j][2] + bv.z, v3 = acc[i][j][3] + bv.w;
                if (wid == 0) {
                    union { __bf16 h[4]; uint2 u; } pk;
                    pk.h[0] = (__bf16)(v0 * QSCALE); pk.h[1] = (__bf16)(v1 * QSCALE);
                    pk.h[2] = (__bf16)(v2 * QSCALE); pk.h[3] = (__bf16)(v3 * QSCALE);
                    *reinterpret_cast<uint2*>(
                        &((__bf16*)o0)[((((size_t)(bI * HH + hh) << 10) + ntok) << 6) + f0]) = pk.u;
                } else if (wid == 1) {
                    union { __bf16 h[4]; uint2 u; } pk;
                    pk.h[0] = (__bf16)v0; pk.h[1] = (__bf16)v1;
                    pk.h[2] = (__bf16)v2; pk.h[3] = (__bf16)v3;
                    *reinterpret_cast<uint2*>(
                        &((__bf16*)o1)[((((size_t)(bI * HH + hh) << 10) + ntok) << 6) + f0]) = pk.u;
                } else {
                    __bf16* vb = (__bf16*)o2;
                    size_t base = ((size_t)(bI * HH + hh) * 64 + f0) << 10;
                    vb[base + ntok] = (__bf16)v0;
                    vb[base + (1 << 10) + ntok] = (__bf16)v1;
                    vb[base + (2 << 10) + ntok] = (__bf16)v2;
                    vb[base + (3 << 10) + ntok] = (__bf16)v3;
                }
            } else if (EPI == 3) {
                const float4 bv = *reinterpret_cast<const float4*>(&b0[n]);
                union { __bf16 h[4]; uint2 u; } pk;
                pk.h[0] = (__bf16)gelu_fast(acc[i][j][0] + bv.x);
                pk.h[1] = (__bf16)gelu_fast(acc[i][j][1] + bv.y);
                pk.h[2] = (__bf16)gelu_fast(acc[i][j][2] + bv.z);
                pk.h[3] = (__bf16)gelu_fast(acc[i][j][3] + bv.w);
                *reinterpret_cast<uint2*>(&((__bf16*)o0)[(size_t)m * MLPD + n]) = pk.u;
            } else {
                const float4 bv = *reinterpret_cast<const float4*>(&b0[n]);
                const float v0 = acc[i][j][0] + bv.x, v1 = acc[i][j][1] + bv.y;
                const float v2 = acc[i][j][2] + bv.z, v3 = acc[i][j][3] + bv.w;
                const float4 rv = *reinterpret_cast<const float4*>(&resid[(size_t)m * DD + n]);
                if (EPI == 2) {
                    float4 ov = {v0 + rv.x, v1 + rv.y, v2 + rv.z, v3 + rv.w};
                    *reinterpret_cast<float4*>(&((float*)o0)[(size_t)m * DD + n]) = ov;
                } else {
                    float4 ov = {gelu_fast(v0) + rv.x, gelu_fast(v1) + rv.y,
                                 gelu_fast(v2) + rv.z, gelu_fast(v3) + rv.w};
                    *reinterpret_cast<float4*>(&((float*)o0)[(size_t)m * DD + n]) = ov;
                }
            }
        }
    }
}

// ---------- flash attention: 128 q-rows/block, 8 waves, dbuf K/V, counted vmcnt,
// XCD-chunked swizzle, no-max softmax, exp/PV interleaved, hard barriers.
__global__ __launch_bounds__(512, 6) void attn_kernel(
    const __bf16* __restrict__ Q, const __bf16* __restrict__ Kg,
    const __bf16* __restrict__ Vt, __bf16* __restrict__ Aout) {
    __shared__ char KsB[2][64 * 128];
    __shared__ char VsB[2][64 * 128];
    __shared__ char PsB[8][16 * 128];
    const int id = blockIdx.x;                 // 768 = 96 bh x 8 qt
    const int swz = (id & 7) * 96 + (id >> 3); // XCD-chunked (768%8==0, bijective)
    const int bh = swz >> 3, qt = swz & 7;
    const int t = threadIdx.x, w = t >> 6, lane = t & 63;
    const int lr = lane & 15, lg = lane >> 4;
    const size_t bhN = (size_t)bh << 10;
    const int q0 = qt * 128;

    bf16x8 qf[2];
#pragma unroll
    for (int kg = 0; kg < 2; ++kg)
        qf[kg] = *reinterpret_cast<const bf16x8*>(&Q[(bhN + q0 + w * 16 + lr) * 64 + kg * 32 + lg * 8]);

    const int srow = t >> 3;
    const int sc = ((t & 7) ^ (srow & 7)) * 16;
    const char* kbase = (const char*)Kg + bhN * 128;
    const char* vbase = (const char*)Vt + ((size_t)bh << 17);
    const int wlds = w * 1024;

    f32x4 oacc[4] = {};
    float lsum[4] = {0.f, 0.f, 0.f, 0.f};

    gload16(kbase + (size_t)srow * 128 + sc, KsB[0] + wlds);
    gload16(vbase + (size_t)srow * 2048 + sc, VsB[0] + wlds);

    for (int kt = 0; kt < 16; ++kt) {
        const int buf = kt & 1;
        if (kt < 15) {
            gload16(kbase + (size_t)((kt + 1) * 64 + srow) * 128 + sc, KsB[buf ^ 1] + wlds);
            gload16(vbase + (size_t)srow * 2048 + (kt + 1) * 128 + sc, VsB[buf ^ 1] + wlds);
            asm volatile("s_waitcnt vmcnt(2)" ::: "memory");
        } else {
            asm volatile("s_waitcnt vmcnt(0)" ::: "memory");
        }
        hard_barrier();

        f32x4 s[4] = {};
        __builtin_amdgcn_s_setprio(1);
#pragma unroll
        for (int kg = 0; kg < 2; ++kg) {
#pragma unroll
            for (int j = 0; j < 4; ++j) {
                int row = j * 16 + lr;
                bf16x8 kf = *reinterpret_cast<const bf16x8*>(
                    KsB[buf] + ((row * 128 + kg * 64 + lg * 16) ^ ((row & 7) << 4)));
                s[j] = __builtin_amdgcn_mfma_f32_16x16x32_bf16(qf[kg], kf, s[j], 0, 0, 0);
            }
        }
        __builtin_amdgcn_s_setprio(0);

#pragma unroll
        for (int r = 0; r < 4; ++r) {
            int prow = lg * 4 + r;
#pragma unroll
            for (int j = 0; j < 2; ++j) {
                float pv = __expf(s[j][r]);
                lsum[r] += pv;
                *reinterpret_cast<__bf16*>(
                    PsB[w] + ((prow * 128 + (j * 16 + lr) * 2) ^ ((prow & 7) << 4))) = (__bf16)pv;
            }
        }
        bf16x8 pf0 = *reinterpret_cast<const bf16x8*>(
            PsB[w] + ((lr * 128 + 0 * 64 + lg * 16) ^ ((lr & 7) << 4)));
#pragma unroll
        for (int r = 0; r < 4; ++r) {
            int prow = lg * 4 + r;
#pragma unroll
            for (int j = 2; j < 4; ++j) {
                float pv = __expf(s[j][r]);
                lsum[r] += pv;
                *reinterpret_cast<__bf16*>(
                    PsB[w] + ((prow * 128 + (j * 16 + lr) * 2) ^ ((prow & 7) << 4))) = (__bf16)pv;
            }
        }
#pragma unroll
        for (int j = 0; j < 4; ++j) {
            int row = j * 16 + lr;
            bf16x8 vf = *reinterpret_cast<const bf16x8*>(
                VsB[buf] + ((row * 128 + 0 * 64 + lg * 16) ^ ((row & 7) << 4)));
            oacc[j] = __builtin_amdgcn_mfma_f32_16x16x32_bf16(pf0, vf, oacc[j], 0, 0, 0);
        }
        bf16x8 pf1 = *reinterpret_cast<const bf16x8*>(
            PsB[w] + ((lr * 128 + 1 * 64 + lg * 16) ^ ((lr & 7) << 4)));
#pragma unroll
        for (int j = 0; j < 4; ++j) {
            int row = j * 16 + lr;
            bf16x8 vf = *reinterpret_cast<const bf16x8*>(
                VsB[buf] + ((row * 128 + 1 * 64 + lg * 16) ^ ((row & 7) << 4)));
            oacc[j] = __builtin_amdgcn_mfma_f32_16x16x32_bf16(pf1, vf, oacc[j], 0, 0, 0);
        }
        hard_barrier();
    }

#pragma unroll
    for (int r = 0; r < 4; ++r)
#pragma unroll
        for (int m = 1; m < 16; m <<= 1) lsum[r] += __shfl_xor(lsum[r], m);

    const int bI = bh / HH, hh = bh % HH;
#pragma unroll
    for (int r = 0; r < 4; ++r) {
        float inv = 1.0f / lsum[r];
        int qrow = q0 + w * 16 + lg * 4 + r;
        size_t base = ((size_t)(bI << 10) + qrow) * DD + hh * 64;
#pragma unroll
        for (int j = 0; j < 4; ++j)
            Aout[base + j * 16 + lr] = (__bf16)(oacc[j][r] * inv);
    }
}

extern "C" void kernel_launch(void* const* d_in, const int* in_sizes, int n_in,
                              void* d_out, int out_size, void* d_ws, size_t ws_size,
                              hipStream_t stream) {
    const float* x     = (const float*)d_in[0];
    const float* ln1_g = (const float*)d_in[1];
    const float* ln1_b = (const float*)d_in[2];
    const float* Wq    = (const float*)d_in[3];
    const float* bq    = (const float*)d_in[4];
    const float* Wk    = (const float*)d_in[5];
    const float* bk    = (const float*)d_in[6];
    const float* Wv    = (const float*)d_in[7];
    const float* bv    = (const float*)d_in[8];
    const float* Wo    = (const float*)d_in[9];
    const float* bo    = (const float*)d_in[10];
    const float* ln2_g = (const float*)d_in[11];
    const float* ln2_b = (const float*)d_in[12];
    const float* W1    = (const float*)d_in[13];
    const float* b1    = (const float*)d_in[14];
    const float* W2    = (const float*)d_in[15];
    const float* b2    = (const float*)d_in[16];

    char* p = (char*)d_ws;
    auto alloc = [&](size_t bytes) { char* r = p; p += bytes; return r; };
    __bf16* wqkv_t = (__bf16*)alloc((size_t)2304 * 768 * 2);
    __bf16* wo_t   = (__bf16*)alloc((size_t)768 * 768 * 2);
    __bf16* w1_t   = (__bf16*)alloc((size_t)3072 * 768 * 2);
    __bf16* w2_t   = (__bf16*)alloc((size_t)768 * 3072 * 2);
    __bf16* h      = (__bf16*)alloc((size_t)8192 * 768 * 2);   // also h2
    float*  outb   = (float*) alloc((size_t)8192 * 768 * 4);
    __bf16* q      = (__bf16*)alloc((size_t)8192 * 768 * 2);
    __bf16* kb     = (__bf16*)alloc((size_t)8192 * 768 * 2);
    __bf16* vt     = (__bf16*)alloc((size_t)8192 * 768 * 2);
    __bf16* attn   = (__bf16*)alloc((size_t)8192 * 768 * 2);
    __bf16* mid    = q;  // alias: q..attn span = 8192*3072*2 bytes, q/k/v dead after attn

    const int LDSP = 65536;   // 2 x (128x64 + 128x64) x 2B = 64 KiB
    hipFuncSetAttribute(reinterpret_cast<const void*>(gemm_pl<0>),
                        hipFuncAttributeMaxDynamicSharedMemorySize, LDSP);
    hipFuncSetAttribute(reinterpret_cast<const void*>(gemm_pl<2>),
                        hipFuncAttributeMaxDynamicSharedMemorySize, LDSP);
    hipFuncSetAttribute(reinterpret_cast<const void*>(gemm_pl<3>),
                        hipFuncAttributeMaxDynamicSharedMemorySize, LDSP);
    hipFuncSetAttribute(reinterpret_cast<const void*>(gemm_pl<4>),
                        hipFuncAttributeMaxDynamicSharedMemorySize, LDSP);

    // fused: weight transposes (blocks 0..1727) + LN1 (blocks 1728..3775)
    prep_kernel<<<3776, 256, 0, stream>>>(Wq, Wk, Wv, Wo, W1, W2,
                                          wqkv_t, wo_t, w1_t, w2_t,
                                          x, ln1_g, ln1_b, h);
    gemm_pl<0><<<1152, 512, LDSP, stream>>>(h, wqkv_t, bq, bk, bv, q, kb, vt,
                                            nullptr, 64, 8192, 2304, 768);
    attn_kernel<<<768, 512, 0, stream>>>(q, kb, vt, attn);
    gemm_pl<2><<<384, 512, LDSP, stream>>>(attn, wo_t, bo, nullptr, nullptr, outb,
                                           nullptr, nullptr, x, 64, 8192, 768, 768);
    ln_kernel<<<2048, 256, 0, stream>>>(outb, ln2_g, ln2_b, h);
    gemm_pl<3><<<1536, 512, LDSP, stream>>>(h, w1_t, b1, nullptr, nullptr, mid,
                                            nullptr, nullptr, nullptr, 64, 8192, 3072, 768);
    gemm_pl<4><<<384, 512, LDSP, stream>>>(mid, w2_t, b2, nullptr, nullptr, (float*)d_out,
                                           nullptr, nullptr, outb, 64, 8192, 768, 3072);
}

// Round 19
// 234.347 us; speedup vs baseline: 1.1259x; 1.1259x over previous
//
#include <hip/hip_runtime.h>
#include <hip/hip_bf16.h>
#include <math.h>

typedef __bf16 bf16x8 __attribute__((ext_vector_type(8)));
typedef float f32x4 __attribute__((ext_vector_type(4)));

#define DD 768
#define HH 12
#define MLPD 3072
#define QSCALE 0.036084391824351615f  // 1/sqrt(768)

// sigmoid-form tanh-approx gelu: max abs err ~3e-4, ~8 VALU ops (1 hw exp)
__device__ __forceinline__ float gelu_fast(float x) {
    float y = 1.5957691216057308f * x + 0.07135481283154893f * x * x * x;
    return x * __builtin_amdgcn_rcpf(1.0f + __expf(-y));
}

__device__ __forceinline__ void gload16(const void* g, void* l) {
    __builtin_amdgcn_global_load_lds(
        (const __attribute__((address_space(1))) unsigned int*)g,
        (__attribute__((address_space(3))) unsigned int*)l, 16, 0, 0);
}

// barrier the compiler cannot reorder memory ops across (rule #18)
__device__ __forceinline__ void hard_barrier() {
    __builtin_amdgcn_sched_barrier(0);
    __builtin_amdgcn_s_barrier();
    __builtin_amdgcn_sched_barrier(0);
}

// ---------- LayerNorm row body: one wave handles one row of 768 ----------
__device__ __forceinline__ void ln_row(const float* __restrict__ xr,
                                       const float* __restrict__ g,
                                       const float* __restrict__ b,
                                       __bf16* __restrict__ orow, int lane) {
    float4 v[3];
    float s = 0.f, ss = 0.f;
#pragma unroll
    for (int i = 0; i < 3; ++i) {
        v[i] = *reinterpret_cast<const float4*>(&xr[(i * 64 + lane) * 4]);
        s += v[i].x + v[i].y + v[i].z + v[i].w;
        ss += v[i].x * v[i].x + v[i].y * v[i].y + v[i].z * v[i].z + v[i].w * v[i].w;
    }
#pragma unroll
    for (int m = 1; m < 64; m <<= 1) {
        s += __shfl_xor(s, m);
        ss += __shfl_xor(ss, m);
    }
    float mu = s * (1.0f / DD);
    float rstd = rsqrtf(ss * (1.0f / DD) - mu * mu + 1e-5f);
#pragma unroll
    for (int i = 0; i < 3; ++i) {
        int c = (i * 64 + lane) * 4;
        float4 gv = *reinterpret_cast<const float4*>(&g[c]);
        float4 bv = *reinterpret_cast<const float4*>(&b[c]);
        union { __bf16 h[4]; uint2 u; } o;
        o.h[0] = (__bf16)((v[i].x - mu) * rstd * gv.x + bv.x);
        o.h[1] = (__bf16)((v[i].y - mu) * rstd * gv.y + bv.y);
        o.h[2] = (__bf16)((v[i].z - mu) * rstd * gv.z + bv.z);
        o.h[3] = (__bf16)((v[i].w - mu) * rstd * gv.w + bv.w);
        *reinterpret_cast<uint2*>(&orow[c]) = o.u;
    }
}

// ---------- standalone LN (4 rows per 256-thr block) for LN2 ----------
__global__ __launch_bounds__(256) void ln_kernel(const float* __restrict__ X,
                                                 const float* __restrict__ g,
                                                 const float* __restrict__ b,
                                                 __bf16* __restrict__ O) {
    int row = blockIdx.x * 4 + (threadIdx.x >> 6);
    ln_row(X + (size_t)row * DD, g, b, O + (size_t)row * DD, threadIdx.x & 63);
}

// ---------- fused prep: blocks [0,1728) weight transposes, [1728,3776) LN1 ----------
__global__ __launch_bounds__(256) void prep_kernel(
    const float* __restrict__ Wq, const float* __restrict__ Wk,
    const float* __restrict__ Wv, const float* __restrict__ Wo,
    const float* __restrict__ W1, const float* __restrict__ W2,
    __bf16* __restrict__ wqkv, __bf16* __restrict__ wo,
    __bf16* __restrict__ w1, __bf16* __restrict__ w2,
    const float* __restrict__ x, const float* __restrict__ ln1_g,
    const float* __restrict__ ln1_b, __bf16* __restrict__ h) {
    __shared__ float tile[64][65];
    int blk = blockIdx.x;
    if (blk >= 1728) {  // LN1: 4 rows per block
        int row = (blk - 1728) * 4 + (threadIdx.x >> 6);
        ln_row(x + (size_t)row * DD, ln1_g, ln1_b, h + (size_t)row * DD, threadIdx.x & 63);
        return;
    }
    const float* W; __bf16* Wt; int K, N, tk, tn;
    if (blk < 432) {
        int wsel = blk / 144, r = blk - wsel * 144;
        W = wsel == 0 ? Wq : (wsel == 1 ? Wk : Wv);
        Wt = wqkv + (size_t)wsel * 768 * 768;
        K = 768; N = 768; tk = r % 12; tn = r / 12;
    } else if (blk < 576) {
        int r = blk - 432; W = Wo; Wt = wo; K = 768; N = 768; tk = r % 12; tn = r / 12;
    } else if (blk < 1152) {
        int r = blk - 576; W = W1; Wt = w1; K = 768; N = 3072; tk = r % 12; tn = r / 12;
    } else {
        int r = blk - 1152; W = W2; Wt = w2; K = 3072; N = 768; tk = r % 48; tn = r / 48;
    }
    int k0 = tk * 64, n0 = tn * 64;
    int t = threadIdx.x;
    int tr = t >> 6, tc = t & 63;
#pragma unroll
    for (int i = 0; i < 16; ++i) {
        int row = i * 4 + tr;
        tile[row][tc] = W[(size_t)(k0 + row) * N + n0 + tc];
    }
    __syncthreads();
#pragma unroll
    for (int i = 0; i < 16; ++i) {
        int row = i * 4 + tr;
        Wt[(size_t)(n0 + row) * K + k0 + tc] = (__bf16)tile[tc][row];
    }
}

// ---------- pipelined GEMM (round-16 engine + A-locality XCD swizzle) ----------
// 128x128 tile, BK=64, 512 threads = 8 waves (2M x 4N); 2 LDS bufs (64 KB).
// XCD swizzle, corrected axis (round-18 lesson): chunk ids per XCD with BY FASTEST
// so each XCD owns a contiguous 8-bx slice of A (1.6 MB, L2-resident all kernel)
// x all by; B streams via L3. (bx-fastest made every XCD stream ALL of A: FETCH
// 63->150 MB, -17%.) nblk % 8 == 0 for all grids -> bijective.
// Depth-1 counted vmcnt(4); hard barriers (rule 18); source-chunk swizzle (rule 21).
// EPI 0: fused QKV.  EPI 2: +resid fp32.  EPI 3: gelu bf16.  EPI 4: gelu+resid fp32.
template <int EPI>
__global__ __launch_bounds__(512, 4) void gemm_pl(
    const __bf16* __restrict__ A, const __bf16* __restrict__ Bt,
    const float* __restrict__ b0, const float* __restrict__ b1, const float* __restrict__ b2,
    void* __restrict__ o0, void* __restrict__ o1, void* __restrict__ o2,
    const float* __restrict__ resid, int gy, int M, int N, int K) {
    extern __shared__ __bf16 lds[];
    __bf16* As = lds;            // 2 x 128x64
    __bf16* Bs = lds + 16384;    // 2 x 128x64
    const int nblk = (M >> 7) * gy;
    const int cpx = nblk >> 3;                       // blocks per XCD chunk
    const int swzid = (blockIdx.x & 7) * cpx + (blockIdx.x >> 3);
    const int bx = swzid / gy, by = swzid % gy;      // by fastest: XCD keeps A-slice hot
    const int t = threadIdx.x;
    const int w = t >> 6, lane = t & 63;
    const int wm = w >> 2, wn = w & 3;   // 2M x 4N
    const int lr = lane & 15, lg = lane >> 4;
    const int m0 = bx * 128, n0 = by * 128;
    const int lrow8 = lane >> 3;
    const int cSwz = ((lane & 7) ^ lrow8) * 8;

    const __bf16* aSrc = A + (size_t)(m0 + w * 16 + lrow8) * K + cSwz;
    const __bf16* bSrc = Bt + (size_t)(n0 + w * 16 + lrow8) * K + cSwz;
    const int ldsW = w * 16 * 64;

    const int nt = K >> 6;
    f32x4 acc[4][2] = {};

    auto stage = [&](int T) {  // 4 loads/thread
        const int buf = (T & 1) * 8192;
#pragma unroll
        for (int c = 0; c < 2; ++c)
            gload16(aSrc + (size_t)(c * 8) * K + T * 64, &As[buf + ldsW + c * 8 * 64]);
#pragma unroll
        for (int c = 0; c < 2; ++c)
            gload16(bSrc + (size_t)(c * 8) * K + T * 64, &Bs[buf + ldsW + c * 8 * 64]);
    };

    stage(0);
    for (int T = 0; T < nt; ++T) {
        if (T + 1 < nt) {
            stage(T + 1);
            asm volatile("s_waitcnt vmcnt(4)" ::: "memory");  // tile T's 4 landed
        } else {
            asm volatile("s_waitcnt vmcnt(0)" ::: "memory");
        }
        hard_barrier();  // all waves' tile-T loads landed; reads pinned below
        const int buf = (T & 1) * 8192;
#pragma unroll
        for (int kg = 0; kg < 2; ++kg) {
            bf16x8 af[4], bfr[2];
#pragma unroll
            for (int i = 0; i < 4; ++i)
                af[i] = *reinterpret_cast<const bf16x8*>(
                    &As[buf + (wm * 64 + i * 16 + lr) * 64 + (((kg << 2) | lg) ^ (lr & 7)) * 8]);
#pragma unroll
            for (int j = 0; j < 2; ++j)
                bfr[j] = *reinterpret_cast<const bf16x8*>(
                    &Bs[buf + (wn * 32 + j * 16 + lr) * 64 + (((kg << 2) | lg) ^ (lr & 7)) * 8]);
#pragma unroll
            for (int i = 0; i < 4; ++i)
#pragma unroll
                for (int j = 0; j < 2; ++j)
                    acc[i][j] = __builtin_amdgcn_mfma_f32_16x16x32_bf16(bfr[j], af[i], acc[i][j], 0, 0, 0);
        }
        hard_barrier();  // reads of buf done before next stage overwrites it
    }

#pragma unroll
    for (int i = 0; i < 4; ++i) {
        const int m = m0 + wm * 64 + i * 16 + lr;
        const int bI = m >> 10, ntok = m & 1023;
#pragma unroll
        for (int j = 0; j < 2; ++j) {
            const int n = n0 + wn * 32 + j * 16 + lg * 4;
            if (EPI == 0) {
                const int wid = n / 768;
                const int cc0 = n - wid * 768;
                const int hh = cc0 >> 6, f0 = cc0 & 63;
                const float* bsel = (wid == 0 ? b0 : (wid == 1 ? b1 : b2));
                const float4 bv = *reinterpret_cast<const float4*>(&bsel[cc0]);
                const float v0 = acc[i][j][0] + bv.x, v1 = acc[i][j][1] + bv.y;
                const float v2 = acc[i][j][2] + bv.z, v3 = acc[i][j][3] + bv.w;
                if (wid == 0) {
                    union { __bf16 h[4]; uint2 u; } pk;
                    pk.h[0] = (__bf16)(v0 * QSCALE); pk.h[1] = (__bf16)(v1 * QSCALE);
                    pk.h[2] = (__bf16)(v2 * QSCALE); pk.h[3] = (__bf16)(v3 * QSCALE);
                    *reinterpret_cast<uint2*>(
                        &((__bf16*)o0)[((((size_t)(bI * HH + hh) << 10) + ntok) << 6) + f0]) = pk.u;
                } else if (wid == 1) {
                    union { __bf16 h[4]; uint2 u; } pk;
                    pk.h[0] = (__bf16)v0; pk.h[1] = (__bf16)v1;
                    pk.h[2] = (__bf16)v2; pk.h[3] = (__bf16)v3;
                    *reinterpret_cast<uint2*>(
                        &((__bf16*)o1)[((((size_t)(bI * HH + hh) << 10) + ntok) << 6) + f0]) = pk.u;
                } else {
                    __bf16* vb = (__bf16*)o2;
                    size_t base = ((size_t)(bI * HH + hh) * 64 + f0) << 10;
                    vb[base + ntok] = (__bf16)v0;
                    vb[base + (1 << 10) + ntok] = (__bf16)v1;
                    vb[base + (2 << 10) + ntok] = (__bf16)v2;
                    vb[base + (3 << 10) + ntok] = (__bf16)v3;
                }
            } else if (EPI == 3) {
                const float4 bv = *reinterpret_cast<const float4*>(&b0[n]);
                union { __bf16 h[4]; uint2 u; } pk;
                pk.h[0] = (__bf16)gelu_fast(acc[i][j][0] + bv.x);
                pk.h[1] = (__bf16)gelu_fast(acc[i][j][1] + bv.y);
                pk.h[2] = (__bf16)gelu_fast(acc[i][j][2] + bv.z);
                pk.h[3] = (__bf16)gelu_fast(acc[i][j][3] + bv.w);
                *reinterpret_cast<uint2*>(&((__bf16*)o0)[(size_t)m * MLPD + n]) = pk.u;
            } else {
                const float4 bv = *reinterpret_cast<const float4*>(&b0[n]);
                const float v0 = acc[i][j][0] + bv.x, v1 = acc[i][j][1] + bv.y;
                const float v2 = acc[i][j][2] + bv.z, v3 = acc[i][j][3] + bv.w;
                const float4 rv = *reinterpret_cast<const float4*>(&resid[(size_t)m * DD + n]);
                if (EPI == 2) {
                    float4 ov = {v0 + rv.x, v1 + rv.y, v2 + rv.z, v3 + rv.w};
                    *reinterpret_cast<float4*>(&((float*)o0)[(size_t)m * DD + n]) = ov;
                } else {
                    float4 ov = {gelu_fast(v0) + rv.x, gelu_fast(v1) + rv.y,
                                 gelu_fast(v2) + rv.z, gelu_fast(v3) + rv.w};
                    *reinterpret_cast<float4*>(&((float*)o0)[(size_t)m * DD + n]) = ov;
                }
            }
        }
    }
}

// ---------- flash attention: 128 q-rows/block, 8 waves, dbuf K/V, counted vmcnt,
// XCD-chunked swizzle, no-max softmax, exp/PV interleaved, hard barriers.
__global__ __launch_bounds__(512, 6) void attn_kernel(
    const __bf16* __restrict__ Q, const __bf16* __restrict__ Kg,
    const __bf16* __restrict__ Vt, __bf16* __restrict__ Aout) {
    __shared__ char KsB[2][64 * 128];
    __shared__ char VsB[2][64 * 128];
    __shared__ char PsB[8][16 * 128];
    const int id = blockIdx.x;                 // 768 = 96 bh x 8 qt
    const int swz = (id & 7) * 96 + (id >> 3); // XCD-chunked (768%8==0, bijective)
    const int bh = swz >> 3, qt = swz & 7;
    const int t = threadIdx.x, w = t >> 6, lane = t & 63;
    const int lr = lane & 15, lg = lane >> 4;
    const size_t bhN = (size_t)bh << 10;
    const int q0 = qt * 128;

    bf16x8 qf[2];
#pragma unroll
    for (int kg = 0; kg < 2; ++kg)
        qf[kg] = *reinterpret_cast<const bf16x8*>(&Q[(bhN + q0 + w * 16 + lr) * 64 + kg * 32 + lg * 8]);

    const int srow = t >> 3;
    const int sc = ((t & 7) ^ (srow & 7)) * 16;
    const char* kbase = (const char*)Kg + bhN * 128;
    const char* vbase = (const char*)Vt + ((size_t)bh << 17);
    const int wlds = w * 1024;

    f32x4 oacc[4] = {};
    float lsum[4] = {0.f, 0.f, 0.f, 0.f};

    gload16(kbase + (size_t)srow * 128 + sc, KsB[0] + wlds);
    gload16(vbase + (size_t)srow * 2048 + sc, VsB[0] + wlds);

    for (int kt = 0; kt < 16; ++kt) {
        const int buf = kt & 1;
        if (kt < 15) {
            gload16(kbase + (size_t)((kt + 1) * 64 + srow) * 128 + sc, KsB[buf ^ 1] + wlds);
            gload16(vbase + (size_t)srow * 2048 + (kt + 1) * 128 + sc, VsB[buf ^ 1] + wlds);
            asm volatile("s_waitcnt vmcnt(2)" ::: "memory");
        } else {
            asm volatile("s_waitcnt vmcnt(0)" ::: "memory");
        }
        hard_barrier();

        f32x4 s[4] = {};
        __builtin_amdgcn_s_setprio(1);
#pragma unroll
        for (int kg = 0; kg < 2; ++kg) {
#pragma unroll
            for (int j = 0; j < 4; ++j) {
                int row = j * 16 + lr;
                bf16x8 kf = *reinterpret_cast<const bf16x8*>(
                    KsB[buf] + ((row * 128 + kg * 64 + lg * 16) ^ ((row & 7) << 4)));
                s[j] = __builtin_amdgcn_mfma_f32_16x16x32_bf16(qf[kg], kf, s[j], 0, 0, 0);
            }
        }
        __builtin_amdgcn_s_setprio(0);

#pragma unroll
        for (int r = 0; r < 4; ++r) {
            int prow = lg * 4 + r;
#pragma unroll
            for (int j = 0; j < 2; ++j) {
                float pv = __expf(s[j][r]);
                lsum[r] += pv;
                *reinterpret_cast<__bf16*>(
                    PsB[w] + ((prow * 128 + (j * 16 + lr) * 2) ^ ((prow & 7) << 4))) = (__bf16)pv;
            }
        }
        bf16x8 pf0 = *reinterpret_cast<const bf16x8*>(
            PsB[w] + ((lr * 128 + 0 * 64 + lg * 16) ^ ((lr & 7) << 4)));
#pragma unroll
        for (int r = 0; r < 4; ++r) {
            int prow = lg * 4 + r;
#pragma unroll
            for (int j = 2; j < 4; ++j) {
                float pv = __expf(s[j][r]);
                lsum[r] += pv;
                *reinterpret_cast<__bf16*>(
                    PsB[w] + ((prow * 128 + (j * 16 + lr) * 2) ^ ((prow & 7) << 4))) = (__bf16)pv;
            }
        }
#pragma unroll
        for (int j = 0; j < 4; ++j) {
            int row = j * 16 + lr;
            bf16x8 vf = *reinterpret_cast<const bf16x8*>(
                VsB[buf] + ((row * 128 + 0 * 64 + lg * 16) ^ ((row & 7) << 4)));
            oacc[j] = __builtin_amdgcn_mfma_f32_16x16x32_bf16(pf0, vf, oacc[j], 0, 0, 0);
        }
        bf16x8 pf1 = *reinterpret_cast<const bf16x8*>(
            PsB[w] + ((lr * 128 + 1 * 64 + lg * 16) ^ ((lr & 7) << 4)));
#pragma unroll
        for (int j = 0; j < 4; ++j) {
            int row = j * 16 + lr;
            bf16x8 vf = *reinterpret_cast<const bf16x8*>(
                VsB[buf] + ((row * 128 + 1 * 64 + lg * 16) ^ ((row & 7) << 4)));
            oacc[j] = __builtin_amdgcn_mfma_f32_16x16x32_bf16(pf1, vf, oacc[j], 0, 0, 0);
        }
        hard_barrier();
    }

#pragma unroll
    for (int r = 0; r < 4; ++r)
#pragma unroll
        for (int m = 1; m < 16; m <<= 1) lsum[r] += __shfl_xor(lsum[r], m);

    const int bI = bh / HH, hh = bh % HH;
#pragma unroll
    for (int r = 0; r < 4; ++r) {
        float inv = 1.0f / lsum[r];
        int qrow = q0 + w * 16 + lg * 4 + r;
        size_t base = ((size_t)(bI << 10) + qrow) * DD + hh * 64;
#pragma unroll
        for (int j = 0; j < 4; ++j)
            Aout[base + j * 16 + lr] = (__bf16)(oacc[j][r] * inv);
    }
}

extern "C" void kernel_launch(void* const* d_in, const int* in_sizes, int n_in,
                              void* d_out, int out_size, void* d_ws, size_t ws_size,
                              hipStream_t stream) {
    const float* x     = (const float*)d_in[0];
    const float* ln1_g = (const float*)d_in[1];
    const float* ln1_b = (const float*)d_in[2];
    const float* Wq    = (const float*)d_in[3];
    const float* bq    = (const float*)d_in[4];
    const float* Wk    = (const float*)d_in[5];
    const float* bk    = (const float*)d_in[6];
    const float* Wv    = (const float*)d_in[7];
    const float* bv    = (const float*)d_in[8];
    const float* Wo    = (const float*)d_in[9];
    const float* bo    = (const float*)d_in[10];
    const float* ln2_g = (const float*)d_in[11];
    const float* ln2_b = (const float*)d_in[12];
    const float* W1    = (const float*)d_in[13];
    const float* b1    = (const float*)d_in[14];
    const float* W2    = (const float*)d_in[15];
    const float* b2    = (const float*)d_in[16];

    char* p = (char*)d_ws;
    auto alloc = [&](size_t bytes) { char* r = p; p += bytes; return r; };
    __bf16* wqkv_t = (__bf16*)alloc((size_t)2304 * 768 * 2);
    __bf16* wo_t   = (__bf16*)alloc((size_t)768 * 768 * 2);
    __bf16* w1_t   = (__bf16*)alloc((size_t)3072 * 768 * 2);
    __bf16* w2_t   = (__bf16*)alloc((size_t)768 * 3072 * 2);
    __bf16* h      = (__bf16*)alloc((size_t)8192 * 768 * 2);   // also h2
    float*  outb   = (float*) alloc((size_t)8192 * 768 * 4);
    __bf16* q      = (__bf16*)alloc((size_t)8192 * 768 * 2);
    __bf16* kb     = (__bf16*)alloc((size_t)8192 * 768 * 2);
    __bf16* vt     = (__bf16*)alloc((size_t)8192 * 768 * 2);
    __bf16* attn   = (__bf16*)alloc((size_t)8192 * 768 * 2);
    __bf16* mid    = q;  // alias: q..attn span = 8192*3072*2 bytes, q/k/v dead after attn

    const int LDSP = 65536;   // 2 x (128x64 + 128x64) x 2B = 64 KiB
    hipFuncSetAttribute(reinterpret_cast<const void*>(gemm_pl<0>),
                        hipFuncAttributeMaxDynamicSharedMemorySize, LDSP);
    hipFuncSetAttribute(reinterpret_cast<const void*>(gemm_pl<2>),
                        hipFuncAttributeMaxDynamicSharedMemorySize, LDSP);
    hipFuncSetAttribute(reinterpret_cast<const void*>(gemm_pl<3>),
                        hipFuncAttributeMaxDynamicSharedMemorySize, LDSP);
    hipFuncSetAttribute(reinterpret_cast<const void*>(gemm_pl<4>),
                        hipFuncAttributeMaxDynamicSharedMemorySize, LDSP);

    // fused: weight transposes (blocks 0..1727) + LN1 (blocks 1728..3775)
    prep_kernel<<<3776, 256, 0, stream>>>(Wq, Wk, Wv, Wo, W1, W2,
                                          wqkv_t, wo_t, w1_t, w2_t,
                                          x, ln1_g, ln1_b, h);
    gemm_pl<0><<<1152, 512, LDSP, stream>>>(h, wqkv_t, bq, bk, bv, q, kb, vt,
                                            nullptr, 18, 8192, 2304, 768);
    attn_kernel<<<768, 512, 0, stream>>>(q, kb, vt, attn);
    gemm_pl<2><<<384, 512, LDSP, stream>>>(attn, wo_t, bo, nullptr, nullptr, outb,
                                           nullptr, nullptr, x, 6, 8192, 768, 768);
    ln_kernel<<<2048, 256, 0, stream>>>(outb, ln2_g, ln2_b, h);
    gemm_pl<3><<<1536, 512, LDSP, stream>>>(h, w1_t, b1, nullptr, nullptr, mid,
                                            nullptr, nullptr, nullptr, 24, 8192, 3072, 768);
    gemm_pl<4><<<384, 512, LDSP, stream>>>(mid, w2_t, b2, nullptr, nullptr, (float*)d_out,
                                           nullptr, nullptr, outb, 6, 8192, 768, 3072);
}

// Round 20
// 226.260 us; speedup vs baseline: 1.1661x; 1.0357x over previous
//
#include <hip/hip_runtime.h>
#include <hip/hip_bf16.h>
#include <math.h>

typedef __bf16 bf16x8 __attribute__((ext_vector_type(8)));
typedef float f32x4 __attribute__((ext_vector_type(4)));

#define DD 768
#define HH 12
#define MLPD 3072
#define QSCALE 0.036084391824351615f  // 1/sqrt(768)

// sigmoid-form tanh-approx gelu: max abs err ~3e-4, ~8 VALU ops (1 hw exp)
__device__ __forceinline__ float gelu_fast(float x) {
    float y = 1.5957691216057308f * x + 0.07135481283154893f * x * x * x;
    return x * __builtin_amdgcn_rcpf(1.0f + __expf(-y));
}

__device__ __forceinline__ void gload16(const void* g, void* l) {
    __builtin_amdgcn_global_load_lds(
        (const __attribute__((address_space(1))) unsigned int*)g,
        (__attribute__((address_space(3))) unsigned int*)l, 16, 0, 0);
}

// barrier the compiler cannot reorder memory ops across (rule #18):
// raw s_barrier is IntrNoMem in LLVM -> pin with sched_barrier(0) on both sides.
__device__ __forceinline__ void hard_barrier() {
    __builtin_amdgcn_sched_barrier(0);
    __builtin_amdgcn_s_barrier();
    __builtin_amdgcn_sched_barrier(0);
}

// ---------- LayerNorm row body: one wave handles one row of 768 ----------
__device__ __forceinline__ void ln_row(const float* __restrict__ xr,
                                       const float* __restrict__ g,
                                       const float* __restrict__ b,
                                       __bf16* __restrict__ orow, int lane) {
    float4 v[3];
    float s = 0.f, ss = 0.f;
#pragma unroll
    for (int i = 0; i < 3; ++i) {
        v[i] = *reinterpret_cast<const float4*>(&xr[(i * 64 + lane) * 4]);
        s += v[i].x + v[i].y + v[i].z + v[i].w;
        ss += v[i].x * v[i].x + v[i].y * v[i].y + v[i].z * v[i].z + v[i].w * v[i].w;
    }
#pragma unroll
    for (int m = 1; m < 64; m <<= 1) {
        s += __shfl_xor(s, m);
        ss += __shfl_xor(ss, m);
    }
    float mu = s * (1.0f / DD);
    float rstd = rsqrtf(ss * (1.0f / DD) - mu * mu + 1e-5f);
#pragma unroll
    for (int i = 0; i < 3; ++i) {
        int c = (i * 64 + lane) * 4;
        float4 gv = *reinterpret_cast<const float4*>(&g[c]);
        float4 bv = *reinterpret_cast<const float4*>(&b[c]);
        union { __bf16 h[4]; uint2 u; } o;
        o.h[0] = (__bf16)((v[i].x - mu) * rstd * gv.x + bv.x);
        o.h[1] = (__bf16)((v[i].y - mu) * rstd * gv.y + bv.y);
        o.h[2] = (__bf16)((v[i].z - mu) * rstd * gv.z + bv.z);
        o.h[3] = (__bf16)((v[i].w - mu) * rstd * gv.w + bv.w);
        *reinterpret_cast<uint2*>(&orow[c]) = o.u;
    }
}

// ---------- standalone LN (4 rows per 256-thr block) for LN2 ----------
__global__ __launch_bounds__(256) void ln_kernel(const float* __restrict__ X,
                                                 const float* __restrict__ g,
                                                 const float* __restrict__ b,
                                                 __bf16* __restrict__ O) {
    int row = blockIdx.x * 4 + (threadIdx.x >> 6);
    ln_row(X + (size_t)row * DD, g, b, O + (size_t)row * DD, threadIdx.x & 63);
}

// ---------- fused prep: blocks [0,1728) weight transposes, [1728,3776) LN1 ----------
__global__ __launch_bounds__(256) void prep_kernel(
    const float* __restrict__ Wq, const float* __restrict__ Wk,
    const float* __restrict__ Wv, const float* __restrict__ Wo,
    const float* __restrict__ W1, const float* __restrict__ W2,
    __bf16* __restrict__ wqkv, __bf16* __restrict__ wo,
    __bf16* __restrict__ w1, __bf16* __restrict__ w2,
    const float* __restrict__ x, const float* __restrict__ ln1_g,
    const float* __restrict__ ln1_b, __bf16* __restrict__ h) {
    __shared__ float tile[64][65];
    int blk = blockIdx.x;
    if (blk >= 1728) {  // LN1: 4 rows per block
        int row = (blk - 1728) * 4 + (threadIdx.x >> 6);
        ln_row(x + (size_t)row * DD, ln1_g, ln1_b, h + (size_t)row * DD, threadIdx.x & 63);
        return;
    }
    const float* W; __bf16* Wt; int K, N, tk, tn;
    if (blk < 432) {
        int wsel = blk / 144, r = blk - wsel * 144;
        W = wsel == 0 ? Wq : (wsel == 1 ? Wk : Wv);
        Wt = wqkv + (size_t)wsel * 768 * 768;
        K = 768; N = 768; tk = r % 12; tn = r / 12;
    } else if (blk < 576) {
        int r = blk - 432; W = Wo; Wt = wo; K = 768; N = 768; tk = r % 12; tn = r / 12;
    } else if (blk < 1152) {
        int r = blk - 576; W = W1; Wt = w1; K = 768; N = 3072; tk = r % 12; tn = r / 12;
    } else {
        int r = blk - 1152; W = W2; Wt = w2; K = 3072; N = 768; tk = r % 48; tn = r / 48;
    }
    int k0 = tk * 64, n0 = tn * 64;
    int t = threadIdx.x;
    int tr = t >> 6, tc = t & 63;
#pragma unroll
    for (int i = 0; i < 16; ++i) {
        int row = i * 4 + tr;
        tile[row][tc] = W[(size_t)(k0 + row) * N + n0 + tc];
    }
    __syncthreads();
#pragma unroll
    for (int i = 0; i < 16; ++i) {
        int row = i * 4 + tr;
        Wt[(size_t)(n0 + row) * K + k0 + tc] = (__bf16)tile[tc][row];
    }
}

// ---------- pipelined GEMM (round-13 engine + hard barriers): 128x128, BK=64 ----------
// 512 threads = 8 waves (2M x 4N), 64x32 out/wave; 2 LDS bufs (64 KB) -> 2 blocks/CU,
// 4 waves/SIMD. Depth-1 counted vmcnt: stage T+1 (4 loads/thread), vmcnt(4) -> tile T
// landed (this wave); hard_barrier -> ALL waves' loads landed AND reads pinned below.
// End hard_barrier seals buf T%2 before iter T+1's stage (gload issue pinned below).
// LDS dest linear, SOURCE chunk-swizzled, reads same XOR (rule 21). No lgkm pins
// inside the MFMA phase (m141 trap) - compiler interleaves ds_read/MFMA itself.
// Default (linear) dispatch order retained: both XCD swizzle variants measured WORSE
// (r18 bx-fastest: FETCH 63->150 MB; r19 by-fastest: 63->81 MB) - linear launch
// already temporally aligns all XCDs on the same B-panel.
// EPI 0: fused QKV.  EPI 2: +resid fp32.  EPI 3: gelu bf16.  EPI 4: gelu+resid fp32.
template <int EPI>
__global__ __launch_bounds__(512, 4) void gemm_pl(
    const __bf16* __restrict__ A, const __bf16* __restrict__ Bt,
    const float* __restrict__ b0, const float* __restrict__ b1, const float* __restrict__ b2,
    void* __restrict__ o0, void* __restrict__ o1, void* __restrict__ o2,
    const float* __restrict__ resid, int M, int N, int K) {
    extern __shared__ __bf16 lds[];
    __bf16* As = lds;            // 2 x 128x64
    __bf16* Bs = lds + 16384;    // 2 x 128x64
    const int t = threadIdx.x;
    const int w = t >> 6, lane = t & 63;
    const int wm = w >> 2, wn = w & 3;   // 2M x 4N
    const int lr = lane & 15, lg = lane >> 4;
    const int m0 = blockIdx.x * 128, n0 = blockIdx.y * 128;
    const int lrow8 = lane >> 3;
    const int cSwz = ((lane & 7) ^ lrow8) * 8;

    // each wave stages 16 rows of A and 16 rows of B (2 gloads each)
    const __bf16* aSrc = A + (size_t)(m0 + w * 16 + lrow8) * K + cSwz;
    const __bf16* bSrc = Bt + (size_t)(n0 + w * 16 + lrow8) * K + cSwz;
    const int ldsW = w * 16 * 64;

    const int nt = K >> 6;
    f32x4 acc[4][2] = {};

    auto stage = [&](int T) {  // 4 loads/thread
        const int buf = (T & 1) * 8192;
#pragma unroll
        for (int c = 0; c < 2; ++c)
            gload16(aSrc + (size_t)(c * 8) * K + T * 64, &As[buf + ldsW + c * 8 * 64]);
#pragma unroll
        for (int c = 0; c < 2; ++c)
            gload16(bSrc + (size_t)(c * 8) * K + T * 64, &Bs[buf + ldsW + c * 8 * 64]);
    };

    stage(0);
    for (int T = 0; T < nt; ++T) {
        if (T + 1 < nt) {
            stage(T + 1);
            asm volatile("s_waitcnt vmcnt(4)" ::: "memory");  // tile T's 4 landed
        } else {
            asm volatile("s_waitcnt vmcnt(0)" ::: "memory");
        }
        hard_barrier();  // all waves' tile-T loads landed; reads pinned below
        const int buf = (T & 1) * 8192;
#pragma unroll
        for (int kg = 0; kg < 2; ++kg) {
            bf16x8 af[4], bfr[2];
#pragma unroll
            for (int i = 0; i < 4; ++i)
                af[i] = *reinterpret_cast<const bf16x8*>(
                    &As[buf + (wm * 64 + i * 16 + lr) * 64 + (((kg << 2) | lg) ^ (lr & 7)) * 8]);
#pragma unroll
            for (int j = 0; j < 2; ++j)
                bfr[j] = *reinterpret_cast<const bf16x8*>(
                    &Bs[buf + (wn * 32 + j * 16 + lr) * 64 + (((kg << 2) | lg) ^ (lr & 7)) * 8]);
#pragma unroll
            for (int i = 0; i < 4; ++i)
#pragma unroll
                for (int j = 0; j < 2; ++j)
                    acc[i][j] = __builtin_amdgcn_mfma_f32_16x16x32_bf16(bfr[j], af[i], acc[i][j], 0, 0, 0);
        }
        hard_barrier();  // reads of buf done before next stage overwrites it
    }

#pragma unroll
    for (int i = 0; i < 4; ++i) {
        const int m = m0 + wm * 64 + i * 16 + lr;
        const int bI = m >> 10, ntok = m & 1023;
#pragma unroll
        for (int j = 0; j < 2; ++j) {
            const int n = n0 + wn * 32 + j * 16 + lg * 4;
            if (EPI == 0) {
                const int wid = n / 768;
                const int cc0 = n - wid * 768;
                const int hh = cc0 >> 6, f0 = cc0 & 63;
                const float* bsel = (wid == 0 ? b0 : (wid == 1 ? b1 : b2));
                const float4 bv = *reinterpret_cast<const float4*>(&bsel[cc0]);
                const float v0 = acc[i][j][0] + bv.x, v1 = acc[i][j][1] + bv.y;
                const float v2 = acc[i][j][2] + bv.z, v3 = acc[i][j][3] + bv.w;
                if (wid == 0) {
                    union { __bf16 h[4]; uint2 u; } pk;
                    pk.h[0] = (__bf16)(v0 * QSCALE); pk.h[1] = (__bf16)(v1 * QSCALE);
                    pk.h[2] = (__bf16)(v2 * QSCALE); pk.h[3] = (__bf16)(v3 * QSCALE);
                    *reinterpret_cast<uint2*>(
                        &((__bf16*)o0)[((((size_t)(bI * HH + hh) << 10) + ntok) << 6) + f0]) = pk.u;
                } else if (wid == 1) {
                    union { __bf16 h[4]; uint2 u; } pk;
                    pk.h[0] = (__bf16)v0; pk.h[1] = (__bf16)v1;
                    pk.h[2] = (__bf16)v2; pk.h[3] = (__bf16)v3;
                    *reinterpret_cast<uint2*>(
                        &((__bf16*)o1)[((((size_t)(bI * HH + hh) << 10) + ntok) << 6) + f0]) = pk.u;
                } else {
                    __bf16* vb = (__bf16*)o2;
                    size_t base = ((size_t)(bI * HH + hh) * 64 + f0) << 10;
                    vb[base + ntok] = (__bf16)v0;
                    vb[base + (1 << 10) + ntok] = (__bf16)v1;
                    vb[base + (2 << 10) + ntok] = (__bf16)v2;
                    vb[base + (3 << 10) + ntok] = (__bf16)v3;
                }
            } else if (EPI == 3) {
                const float4 bv = *reinterpret_cast<const float4*>(&b0[n]);
                union { __bf16 h[4]; uint2 u; } pk;
                pk.h[0] = (__bf16)gelu_fast(acc[i][j][0] + bv.x);
                pk.h[1] = (__bf16)gelu_fast(acc[i][j][1] + bv.y);
                pk.h[2] = (__bf16)gelu_fast(acc[i][j][2] + bv.z);
                pk.h[3] = (__bf16)gelu_fast(acc[i][j][3] + bv.w);
                *reinterpret_cast<uint2*>(&((__bf16*)o0)[(size_t)m * MLPD + n]) = pk.u;
            } else {
                const float4 bv = *reinterpret_cast<const float4*>(&b0[n]);
                const float v0 = acc[i][j][0] + bv.x, v1 = acc[i][j][1] + bv.y;
                const float v2 = acc[i][j][2] + bv.z, v3 = acc[i][j][3] + bv.w;
                const float4 rv = *reinterpret_cast<const float4*>(&resid[(size_t)m * DD + n]);
                if (EPI == 2) {
                    float4 ov = {v0 + rv.x, v1 + rv.y, v2 + rv.z, v3 + rv.w};
                    *reinterpret_cast<float4*>(&((float*)o0)[(size_t)m * DD + n]) = ov;
                } else {
                    float4 ov = {gelu_fast(v0) + rv.x, gelu_fast(v1) + rv.y,
                                 gelu_fast(v2) + rv.z, gelu_fast(v3) + rv.w};
                    *reinterpret_cast<float4*>(&((float*)o0)[(size_t)m * DD + n]) = ov;
                }
            }
        }
    }
}

// ---------- flash attention: 128 q-rows/block, 8 waves, dbuf K/V, counted vmcnt,
// XCD-chunked swizzle, no-max softmax, exp/PV interleaved, hard barriers.
__global__ __launch_bounds__(512, 6) void attn_kernel(
    const __bf16* __restrict__ Q, const __bf16* __restrict__ Kg,
    const __bf16* __restrict__ Vt, __bf16* __restrict__ Aout) {
    __shared__ char KsB[2][64 * 128];
    __shared__ char VsB[2][64 * 128];
    __shared__ char PsB[8][16 * 128];
    const int id = blockIdx.x;                 // 768 = 96 bh x 8 qt
    const int swz = (id & 7) * 96 + (id >> 3); // XCD-chunked (768%8==0, bijective)
    const int bh = swz >> 3, qt = swz & 7;
    const int t = threadIdx.x, w = t >> 6, lane = t & 63;
    const int lr = lane & 15, lg = lane >> 4;
    const size_t bhN = (size_t)bh << 10;
    const int q0 = qt * 128;

    bf16x8 qf[2];
#pragma unroll
    for (int kg = 0; kg < 2; ++kg)
        qf[kg] = *reinterpret_cast<const bf16x8*>(&Q[(bhN + q0 + w * 16 + lr) * 64 + kg * 32 + lg * 8]);

    const int srow = t >> 3;
    const int sc = ((t & 7) ^ (srow & 7)) * 16;
    const char* kbase = (const char*)Kg + bhN * 128;
    const char* vbase = (const char*)Vt + ((size_t)bh << 17);
    const int wlds = w * 1024;

    f32x4 oacc[4] = {};
    float lsum[4] = {0.f, 0.f, 0.f, 0.f};

    gload16(kbase + (size_t)srow * 128 + sc, KsB[0] + wlds);
    gload16(vbase + (size_t)srow * 2048 + sc, VsB[0] + wlds);

    for (int kt = 0; kt < 16; ++kt) {
        const int buf = kt & 1;
        if (kt < 15) {
            gload16(kbase + (size_t)((kt + 1) * 64 + srow) * 128 + sc, KsB[buf ^ 1] + wlds);
            gload16(vbase + (size_t)srow * 2048 + (kt + 1) * 128 + sc, VsB[buf ^ 1] + wlds);
            asm volatile("s_waitcnt vmcnt(2)" ::: "memory");
        } else {
            asm volatile("s_waitcnt vmcnt(0)" ::: "memory");
        }
        hard_barrier();

        f32x4 s[4] = {};
        __builtin_amdgcn_s_setprio(1);
#pragma unroll
        for (int kg = 0; kg < 2; ++kg) {
#pragma unroll
            for (int j = 0; j < 4; ++j) {
                int row = j * 16 + lr;
                bf16x8 kf = *reinterpret_cast<const bf16x8*>(
                    KsB[buf] + ((row * 128 + kg * 64 + lg * 16) ^ ((row & 7) << 4)));
                s[j] = __builtin_amdgcn_mfma_f32_16x16x32_bf16(qf[kg], kf, s[j], 0, 0, 0);
            }
        }
        __builtin_amdgcn_s_setprio(0);

        // softmax half 1 (toks 0..31): exp j=0,1, write P
#pragma unroll
        for (int r = 0; r < 4; ++r) {
            int prow = lg * 4 + r;
#pragma unroll
            for (int j = 0; j < 2; ++j) {
                float pv = __expf(s[j][r]);
                lsum[r] += pv;
                *reinterpret_cast<__bf16*>(
                    PsB[w] + ((prow * 128 + (j * 16 + lr) * 2) ^ ((prow & 7) << 4))) = (__bf16)pv;
            }
        }
        bf16x8 pf0 = *reinterpret_cast<const bf16x8*>(
            PsB[w] + ((lr * 128 + 0 * 64 + lg * 16) ^ ((lr & 7) << 4)));
        // softmax half 2 (toks 32..63): independent -> overlaps PV kg0
#pragma unroll
        for (int r = 0; r < 4; ++r) {
            int prow = lg * 4 + r;
#pragma unroll
            for (int j = 2; j < 4; ++j) {
                float pv = __expf(s[j][r]);
                lsum[r] += pv;
                *reinterpret_cast<__bf16*>(
                    PsB[w] + ((prow * 128 + (j * 16 + lr) * 2) ^ ((prow & 7) << 4))) = (__bf16)pv;
            }
        }
#pragma unroll
        for (int j = 0; j < 4; ++j) {
            int row = j * 16 + lr;
            bf16x8 vf = *reinterpret_cast<const bf16x8*>(
                VsB[buf] + ((row * 128 + 0 * 64 + lg * 16) ^ ((row & 7) << 4)));
            oacc[j] = __builtin_amdgcn_mfma_f32_16x16x32_bf16(pf0, vf, oacc[j], 0, 0, 0);
        }
        bf16x8 pf1 = *reinterpret_cast<const bf16x8*>(
            PsB[w] + ((lr * 128 + 1 * 64 + lg * 16) ^ ((lr & 7) << 4)));
#pragma unroll
        for (int j = 0; j < 4; ++j) {
            int row = j * 16 + lr;
            bf16x8 vf = *reinterpret_cast<const bf16x8*>(
                VsB[buf] + ((row * 128 + 1 * 64 + lg * 16) ^ ((row & 7) << 4)));
            oacc[j] = __builtin_amdgcn_mfma_f32_16x16x32_bf16(pf1, vf, oacc[j], 0, 0, 0);
        }
        hard_barrier();
    }

#pragma unroll
    for (int r = 0; r < 4; ++r)
#pragma unroll
        for (int m = 1; m < 16; m <<= 1) lsum[r] += __shfl_xor(lsum[r], m);

    const int bI = bh / HH, hh = bh % HH;
#pragma unroll
    for (int r = 0; r < 4; ++r) {
        float inv = 1.0f / lsum[r];
        int qrow = q0 + w * 16 + lg * 4 + r;
        size_t base = ((size_t)(bI << 10) + qrow) * DD + hh * 64;
#pragma unroll
        for (int j = 0; j < 4; ++j)
            Aout[base + j * 16 + lr] = (__bf16)(oacc[j][r] * inv);
    }
}

extern "C" void kernel_launch(void* const* d_in, const int* in_sizes, int n_in,
                              void* d_out, int out_size, void* d_ws, size_t ws_size,
                              hipStream_t stream) {
    const float* x     = (const float*)d_in[0];
    const float* ln1_g = (const float*)d_in[1];
    const float* ln1_b = (const float*)d_in[2];
    const float* Wq    = (const float*)d_in[3];
    const float* bq    = (const float*)d_in[4];
    const float* Wk    = (const float*)d_in[5];
    const float* bk    = (const float*)d_in[6];
    const float* Wv    = (const float*)d_in[7];
    const float* bv    = (const float*)d_in[8];
    const float* Wo    = (const float*)d_in[9];
    const float* bo    = (const float*)d_in[10];
    const float* ln2_g = (const float*)d_in[11];
    const float* ln2_b = (const float*)d_in[12];
    const float* W1    = (const float*)d_in[13];
    const float* b1    = (const float*)d_in[14];
    const float* W2    = (const float*)d_in[15];
    const float* b2    = (const float*)d_in[16];

    char* p = (char*)d_ws;
    auto alloc = [&](size_t bytes) { char* r = p; p += bytes; return r; };
    __bf16* wqkv_t = (__bf16*)alloc((size_t)2304 * 768 * 2);
    __bf16* wo_t   = (__bf16*)alloc((size_t)768 * 768 * 2);
    __bf16* w1_t   = (__bf16*)alloc((size_t)3072 * 768 * 2);
    __bf16* w2_t   = (__bf16*)alloc((size_t)768 * 3072 * 2);
    __bf16* h      = (__bf16*)alloc((size_t)8192 * 768 * 2);   // also h2
    float*  outb   = (float*) alloc((size_t)8192 * 768 * 4);
    __bf16* q      = (__bf16*)alloc((size_t)8192 * 768 * 2);
    __bf16* kb     = (__bf16*)alloc((size_t)8192 * 768 * 2);
    __bf16* vt     = (__bf16*)alloc((size_t)8192 * 768 * 2);
    __bf16* attn   = (__bf16*)alloc((size_t)8192 * 768 * 2);
    __bf16* mid    = q;  // alias: q..attn span = 8192*3072*2 bytes, q/k/v dead after attn

    const int LDSP = 65536;   // 2 x (128x64 + 128x64) x 2B = 64 KiB
    hipFuncSetAttribute(reinterpret_cast<const void*>(gemm_pl<0>),
                        hipFuncAttributeMaxDynamicSharedMemorySize, LDSP);
    hipFuncSetAttribute(reinterpret_cast<const void*>(gemm_pl<2>),
                        hipFuncAttributeMaxDynamicSharedMemorySize, LDSP);
    hipFuncSetAttribute(reinterpret_cast<const void*>(gemm_pl<3>),
                        hipFuncAttributeMaxDynamicSharedMemorySize, LDSP);
    hipFuncSetAttribute(reinterpret_cast<const void*>(gemm_pl<4>),
                        hipFuncAttributeMaxDynamicSharedMemorySize, LDSP);

    // fused: weight transposes (blocks 0..1727) + LN1 (blocks 1728..3775)
    prep_kernel<<<3776, 256, 0, stream>>>(Wq, Wk, Wv, Wo, W1, W2,
                                          wqkv_t, wo_t, w1_t, w2_t,
                                          x, ln1_g, ln1_b, h);
    gemm_pl<0><<<dim3(64, 18), 512, LDSP, stream>>>(h, wqkv_t, bq, bk, bv, q, kb, vt,
                                                    nullptr, 8192, 2304, 768);
    attn_kernel<<<768, 512, 0, stream>>>(q, kb, vt, attn);
    gemm_pl<2><<<dim3(64, 6), 512, LDSP, stream>>>(attn, wo_t, bo, nullptr, nullptr, outb,
                                                   nullptr, nullptr, x, 8192, 768, 768);
    ln_kernel<<<2048, 256, 0, stream>>>(outb, ln2_g, ln2_b, h);
    gemm_pl<3><<<dim3(64, 24), 512, LDSP, stream>>>(h, w1_t, b1, nullptr, nullptr, mid,
                                                    nullptr, nullptr, nullptr, 8192, 3072, 768);
    gemm_pl<4><<<dim3(64, 6), 512, LDSP, stream>>>(mid, w2_t, b2, nullptr, nullptr, (float*)d_out,
                                                   nullptr, nullptr, outb, 8192, 768, 3072);
}